// Round 2
// baseline (2184.360 us; speedup 1.0000x reference)
//
#include <hip/hip_runtime.h>
#include <cstdint>
#include <cstddef>

#define BN 64
#define TN 512
#define DN 256
#define UN 256
#define NC 768            // 3*UN, order: r | z | h
#define SLOTS (TN + 5)    // slots TN..TN+3 = initial states, TN+4 = zero slot
#define ZSLOT (TN + 4)

#define NT 512            // threads per block in recurrent kernel (8 waves)
#define RREG 8            // rows per wave-slice of Ur/Uz resident in registers
#define RLDS 6            // rows resident in LDS
#define RSTR 18           // rows streamed from L2 (32 - RREG - RLDS)

__device__ __forceinline__ float sigm(float x) {
  return 1.0f / (1.0f + __expf(-x));
}
__device__ __forceinline__ float tanh_fast(float x) {
  float e = __expf(-2.0f * x);
  return 2.0f / (1.0f + e) - 1.0f;
}

// ---------------- kernel 0: concat weights + biases ----------------
__global__ __launch_bounds__(256) void build_wcat(
    const float* __restrict__ Wr, const float* __restrict__ Wz, const float* __restrict__ Wh,
    const float* __restrict__ br, const float* __restrict__ bz, const float* __restrict__ bh,
    float* __restrict__ wcat, float* __restrict__ bias)
{
  int idx = blockIdx.x * 256 + threadIdx.x;
  if (idx < DN * NC) {
    int k = idx / NC, c = idx % NC;
    float v;
    if (c < 256)      v = Wr[k * UN + c];
    else if (c < 512) v = Wz[k * UN + (c - 256)];
    else              v = Wh[k * UN + (c - 512)];
    wcat[idx] = v;
  }
  if (idx < NC) {
    bias[idx] = (idx < 256) ? br[idx] : ((idx < 512) ? bz[idx - 256] : bh[idx - 512]);
  }
}

// ---------------- kernel 1: P = X @ Wcat + bias  (fp32, LDS-tiled) ----------------
__global__ __launch_bounds__(256) void gemm_xw(
    const float* __restrict__ X, const float* __restrict__ Wc,
    const float* __restrict__ bias, float* __restrict__ P)
{
  __shared__ float As[32][68];
  __shared__ float Bs[32][64];
  const int tid = threadIdx.x;
  const int m0 = blockIdx.x * 64;
  const int n0 = blockIdx.y * 64;
  const int ty = tid >> 4, tx = tid & 15;
  float acc[4][4] = {};

  const int ar = tid >> 3;
  const int ak = (tid & 7) * 4;
  const int bk = tid >> 4;
  const int bn = (tid & 15) * 4;

  for (int k0 = 0; k0 < DN; k0 += 32) {
    float4 a0 = *(const float4*)(X + (size_t)(m0 + ar) * DN + k0 + ak);
    float4 a1 = *(const float4*)(X + (size_t)(m0 + 32 + ar) * DN + k0 + ak);
    As[ak + 0][ar] = a0.x; As[ak + 1][ar] = a0.y; As[ak + 2][ar] = a0.z; As[ak + 3][ar] = a0.w;
    As[ak + 0][32 + ar] = a1.x; As[ak + 1][32 + ar] = a1.y; As[ak + 2][32 + ar] = a1.z; As[ak + 3][32 + ar] = a1.w;
    *(float4*)&Bs[bk][bn]      = *(const float4*)(Wc + (size_t)(k0 + bk) * NC + n0 + bn);
    *(float4*)&Bs[bk + 16][bn] = *(const float4*)(Wc + (size_t)(k0 + bk + 16) * NC + n0 + bn);
    __syncthreads();
#pragma unroll
    for (int kk = 0; kk < 32; kk++) {
      float4 av = *(const float4*)&As[kk][ty * 4];
      float4 bv = *(const float4*)&Bs[kk][tx * 4];
      acc[0][0] += av.x * bv.x; acc[0][1] += av.x * bv.y; acc[0][2] += av.x * bv.z; acc[0][3] += av.x * bv.w;
      acc[1][0] += av.y * bv.x; acc[1][1] += av.y * bv.y; acc[1][2] += av.y * bv.z; acc[1][3] += av.y * bv.w;
      acc[2][0] += av.z * bv.x; acc[2][1] += av.z * bv.y; acc[2][2] += av.z * bv.z; acc[2][3] += av.z * bv.w;
      acc[3][0] += av.w * bv.x; acc[3][1] += av.w * bv.y; acc[3][2] += av.w * bv.z; acc[3][3] += av.w * bv.w;
    }
    __syncthreads();
  }
  float4 bb = *(const float4*)(bias + n0 + tx * 4);
#pragma unroll
  for (int i = 0; i < 4; i++) {
    float4 o;
    o.x = acc[i][0] + bb.x; o.y = acc[i][1] + bb.y;
    o.z = acc[i][2] + bb.z; o.w = acc[i][3] + bb.w;
    *(float4*)(P + (size_t)(m0 + ty * 4 + i) * NC + n0 + tx * 4) = o;
  }
}

// ---------------- kernel 2: the recurrence, one block per batch ----------------
// 512 threads = 8 waves. D-phase: wave wv owns rows [32wv, 32wv+32) of Ur AND Uz; lane owns
// 4 output cols. Rows 0-7 of the slice live in registers, rows 8-13 in LDS, rows 14-31
// streamed fp32 from L2 (288 KB/step instead of 512 KB). Uh fully register-resident.
__global__ __launch_bounds__(NT, 2) void recurrent_kernel(
    const float* __restrict__ P,
    const float* __restrict__ Ur, const float* __restrict__ Uz, const float* __restrict__ Uh,
    const int* __restrict__ dep, const int* __restrict__ mask,
    const float* __restrict__ init,
    float* __restrict__ out,
    float* __restrict__ buf_s, float* __restrict__ buf_pr, float* __restrict__ buf_pz)
{
  const int b = blockIdx.x;
  const int tid = threadIdx.x;
  const int g2 = tid >> 8;          // 0..1
  const int u = tid & 255;
  const int wv = tid >> 6;          // 0..7
  const int lane = tid & 63;
  const int c4 = lane * 4;          // D-phase output col base

  // --- Uh fully resident: column u, k in [128*g2, 128*g2+128) ---
  float wh[128];
  {
    const float* p2 = Uh + (size_t)(128 * g2) * UN + u;
#pragma unroll
    for (int kk = 0; kk < 128; kk++) {
      wh[kk] = p2[(size_t)kk * UN];
    }
  }
  // --- Ur/Uz register-resident rows: global rows 32*wv + [0, RREG), cols [c4, c4+4) ---
  float4 wrgR[RREG], wrgZ[RREG];
  {
    const float4* pR = (const float4*)Ur + (size_t)(32 * wv) * 64 + lane;
    const float4* pZ = (const float4*)Uz + (size_t)(32 * wv) * 64 + lane;
#pragma unroll
    for (int r = 0; r < RREG; r++) {
      wrgR[r] = pR[(size_t)r * 64];
      wrgZ[r] = pZ[(size_t)r * 64];
    }
  }

  __shared__ float4 wlds[2 * RLDS * 8 * 64];   // 96 KB: LDS-resident weight rows
  __shared__ float ls[4][256], lpr[4][256], lpz[4][256];
  __shared__ float lx[NC];
  __shared__ float rs[256], hs[256], zv[256];
  __shared__ float red0[2][256];
  __shared__ float redd2[2][8][256];
  __shared__ float scur[256], prcur[256], pzcur[256];
  __shared__ int eff[TN];
  __shared__ int mloc[TN];
  __shared__ int deploc[TN * 3];

  // --- stage LDS-resident weight rows: global rows 32*wv + RREG + [0, RLDS) ---
  {
    const float4* pR = (const float4*)Ur + (size_t)(32 * wv + RREG) * 64 + lane;
    const float4* pZ = (const float4*)Uz + (size_t)(32 * wv + RREG) * 64 + lane;
#pragma unroll
    for (int r = 0; r < RLDS; r++) {
      wlds[((0 * RLDS + r) * 8 + wv) * 64 + lane] = pR[(size_t)r * 64];
      wlds[((1 * RLDS + r) * 8 + wv) * 64 + lane] = pZ[(size_t)r * 64];
    }
  }

  for (int i = tid; i < TN; i += NT) mloc[i] = mask[b * TN + i];
  for (int i = tid; i < TN * 3; i += NT) deploc[i] = dep[i];

  const size_t bufBase = (size_t)b * SLOTS * UN;

  // prologue: stage initial states, zero slot, current-state LDS
  {
#pragma unroll
    for (int gi = 0; gi < 2; gi++) {
      int gg = gi * 2 + g2;
      float v = init[((size_t)gg * BN + b) * UN + u];
      ls[gg][u] = v;
      buf_s[bufBase + (size_t)(TN + gg) * UN + u] = v;
    }
    if (tid < 256) {
      scur[u] = 0.0f; prcur[u] = 0.0f; pzcur[u] = 0.0f;
      buf_s[bufBase + (size_t)ZSLOT * UN + u] = 0.0f;
      buf_pr[bufBase + (size_t)ZSLOT * UN + u] = 0.0f;
      buf_pz[bufBase + (size_t)ZSLOT * UN + u] = 0.0f;
    }
  }
  __syncthreads();

  // eff[] is a pure function of mask: precompute once (masked steps need no barrier)
  if (tid == 0) {
    int e = ZSLOT;
    for (int t2 = 0; t2 < TN; t2++) { if (mloc[t2]) e = t2; eff[t2] = e; }
  }

  // ---- projection of a 256-vector (in LDS) through Ur|Uz: reg + LDS + stream parts ----
  auto proj2 = [&](const float* hsrc) {
    float4 aR = {0, 0, 0, 0}, aZ = {0, 0, 0, 0};
    const float* hb = hsrc + 32 * wv;
#pragma unroll
    for (int r = 0; r < RREG; r++) {
      float hk = hb[r];
      aR.x = fmaf(hk, wrgR[r].x, aR.x); aR.y = fmaf(hk, wrgR[r].y, aR.y);
      aR.z = fmaf(hk, wrgR[r].z, aR.z); aR.w = fmaf(hk, wrgR[r].w, aR.w);
      aZ.x = fmaf(hk, wrgZ[r].x, aZ.x); aZ.y = fmaf(hk, wrgZ[r].y, aZ.y);
      aZ.z = fmaf(hk, wrgZ[r].z, aZ.z); aZ.w = fmaf(hk, wrgZ[r].w, aZ.w);
    }
#pragma unroll
    for (int r = 0; r < RLDS; r++) {
      float hk = hb[RREG + r];
      float4 w0 = wlds[((0 * RLDS + r) * 8 + wv) * 64 + lane];
      float4 w1 = wlds[((1 * RLDS + r) * 8 + wv) * 64 + lane];
      aR.x = fmaf(hk, w0.x, aR.x); aR.y = fmaf(hk, w0.y, aR.y);
      aR.z = fmaf(hk, w0.z, aR.z); aR.w = fmaf(hk, w0.w, aR.w);
      aZ.x = fmaf(hk, w1.x, aZ.x); aZ.y = fmaf(hk, w1.y, aZ.y);
      aZ.z = fmaf(hk, w1.z, aZ.z); aZ.w = fmaf(hk, w1.w, aZ.w);
    }
    const float4* pR = (const float4*)Ur + (size_t)(32 * wv + RREG + RLDS) * 64 + lane;
    const float4* pZ = (const float4*)Uz + (size_t)(32 * wv + RREG + RLDS) * 64 + lane;
#pragma unroll 6
    for (int r = 0; r < RSTR; r++) {
      float hk = hb[RREG + RLDS + r];
      float4 w0 = pR[(size_t)r * 64];
      float4 w1 = pZ[(size_t)r * 64];
      aR.x = fmaf(hk, w0.x, aR.x); aR.y = fmaf(hk, w0.y, aR.y);
      aR.z = fmaf(hk, w0.z, aR.z); aR.w = fmaf(hk, w0.w, aR.w);
      aZ.x = fmaf(hk, w1.x, aZ.x); aZ.y = fmaf(hk, w1.y, aZ.y);
      aZ.z = fmaf(hk, w1.z, aZ.z); aZ.w = fmaf(hk, w1.w, aZ.w);
    }
    *(float4*)&redd2[0][wv][c4] = aR;
    *(float4*)&redd2[1][wv][c4] = aZ;
  };

  // initial-state projections through Ur|Uz (exact fp32)
#pragma unroll 1
  for (int gg = 0; gg < 4; gg++) {
    proj2(ls[gg]);
    __syncthreads();
    if (tid < 256) {
      float prn = 0.0f, pzn = 0.0f;
#pragma unroll
      for (int q = 0; q < 8; q++) { prn += redd2[0][q][tid]; pzn += redd2[1][q][tid]; }
      buf_pr[bufBase + (size_t)(TN + gg) * UN + tid] = prn;
      buf_pz[bufBase + (size_t)(TN + gg) * UN + tid] = pzn;
    }
    __syncthreads();
  }

  const size_t outB = (size_t)b * TN * UN;
  const size_t pB = (size_t)b * TN * NC;

#pragma unroll 1
  for (int t = 0; t < TN; t++) {
    const int m = mloc[t];   // block-uniform
    if (m == 0) {
      if (tid < 256) out[outB + (size_t)t * UN + u] = 0.0f;
      continue;              // eff precomputed: no barrier needed
    }
    // ---- A: gather 4 source states + cached projections + x-row ----
#pragma unroll
    for (int gi = 0; gi < 2; gi++) {
      int gg = gi * 2 + g2;
      if (t > 0 && gg == 0) {
        ls[0][u] = scur[u]; lpr[0][u] = prcur[u]; lpz[0][u] = pzcur[u];
      } else {
        int src = (t == 0) ? (TN + gg) : eff[deploc[(t - 1) * 3 + (gg - 1)]];
        size_t base = bufBase + (size_t)src * UN + u;
        ls[gg][u]  = buf_s[base];
        lpr[gg][u] = buf_pr[base];
        lpz[gg][u] = buf_pz[base];
      }
    }
    for (int i = tid; i < NC; i += NT) lx[i] = P[pB + (size_t)t * NC + i];
    __syncthreads();
    // ---- A': gates (elementwise) ----
    if (tid < 256) {
      float s0 = ls[0][u], s1 = ls[1][u], s2 = ls[2][u], s3 = ls[3][u];
      float xr = lx[u];
      float r0 = sigm(xr + lpr[0][u]);
      float r1 = sigm(xr + lpr[1][u]);
      float r2 = sigm(xr + lpr[2][u]);
      float r3 = sigm(xr + lpr[3][u]);
      rs[u] = r0 * s0 + r1 * s1 + r2 * s2 + r3 * s3;
      hs[u] = (s0 + s1) + (s2 + s3);
      zv[u] = sigm(lx[256 + u] + ((lpz[0][u] + lpz[1][u]) + (lpz[2][u] + lpz[3][u])));
    }
    __syncthreads();
    // ---- B: live matvec rs @ Uh (register-resident Uh, fp32) ----
    {
      float a0 = 0, a1 = 0, a2 = 0, a3 = 0;
      const float4* v4 = (const float4*)&rs[128 * g2];
#pragma unroll
      for (int kk = 0; kk < 32; kk++) {
        float4 v = v4[kk];
        a0 += v.x * wh[4 * kk];     a1 += v.y * wh[4 * kk + 1];
        a2 += v.z * wh[4 * kk + 2]; a3 += v.w * wh[4 * kk + 3];
      }
      red0[g2][u] = (a0 + a1) + (a2 + a3);
    }
    __syncthreads();
    // ---- C: h, output ----
    if (tid < 256) {
      float ht = tanh_fast(lx[512 + u] + (red0[0][u] + red0[1][u]));
      float z = zv[u];
      float h = z * hs[u] * 0.25f + (1.0f - z) * ht;
      scur[u] = h;
      out[outB + (size_t)t * UN + u] = h;
    }
    __syncthreads();
    // ---- D: projections of new state through Ur|Uz (reg/LDS-resident + 288 KB stream) ----
    proj2(scur);
    __syncthreads();
    // ---- E: commit state + cached projections ----
    if (tid < 256) {
      float prn = 0.0f, pzn = 0.0f;
#pragma unroll
      for (int q = 0; q < 8; q++) { prn += redd2[0][q][tid]; pzn += redd2[1][q][tid]; }
      prcur[tid] = prn; pzcur[tid] = pzn;
      size_t base = bufBase + (size_t)t * UN + tid;
      buf_s[base]  = scur[tid];
      buf_pr[base] = prn;
      buf_pz[base] = pzn;
    }
    __syncthreads();
  }

  // epilogue: last_out, last_state
  if (tid < 256) {
    float lst = scur[u];
    out[(size_t)BN * TN * UN + (size_t)b * UN + u] = mloc[TN - 1] ? lst : 0.0f;
    out[(size_t)BN * TN * UN + (size_t)BN * UN + (size_t)b * UN + u] = lst;
  }
}

extern "C" void kernel_launch(void* const* d_in, const int* in_sizes, int n_in,
                              void* d_out, int out_size, void* d_ws, size_t ws_size,
                              hipStream_t stream) {
  const float* inputs       = (const float*)d_in[0];
  const int*   dependencies = (const int*)d_in[1];
  const int*   mask         = (const int*)d_in[2];
  const float* initial      = (const float*)d_in[3];
  const float* Wz = (const float*)d_in[4];
  const float* Wr = (const float*)d_in[5];
  const float* Wh = (const float*)d_in[6];
  const float* Uz = (const float*)d_in[7];
  const float* Ur = (const float*)d_in[8];
  const float* Uh = (const float*)d_in[9];
  const float* bz = (const float*)d_in[10];
  const float* br = (const float*)d_in[11];
  const float* bh = (const float*)d_in[12];

  float* out = (float*)d_out;
  float* ws  = (float*)d_ws;
  float* wcat    = ws;                                   // 256*768
  float* bias    = wcat + (size_t)DN * NC;               // 768
  float* precomp = bias + NC;                            // B*T*768
  float* buf_s   = precomp + (size_t)BN * TN * NC;       // B*SLOTS*256 each
  float* buf_pr  = buf_s + (size_t)BN * SLOTS * UN;
  float* buf_pz  = buf_pr + (size_t)BN * SLOTS * UN;

  build_wcat<<<(DN * NC + 255) / 256, 256, 0, stream>>>(Wr, Wz, Wh, br, bz, bh, wcat, bias);
  gemm_xw<<<dim3(BN * TN / 64, NC / 64), 256, 0, stream>>>(inputs, wcat, bias, precomp);
  recurrent_kernel<<<BN, NT, 0, stream>>>(precomp, Ur, Uz, Uh, dependencies, mask, initial,
                                          out, buf_s, buf_pr, buf_pz);
}